// Round 3
// baseline (84.218 us; speedup 1.0000x reference)
//
#include <hip/hip_runtime.h>
#include <math.h>

#define BLOCK 128
#define MPT 4          // m-points per thread (BLOCK * MPT = M = 512)
#define NSPLIT 16
#define CHUNK 8

#if __has_builtin(__builtin_amdgcn_exp2f)
#define EXP2F(x) __builtin_amdgcn_exp2f(x)
#else
#define EXP2F(x) exp2f(x)
#endif

// Precompute per-sample constants packed as float4:
//   a = 2t*sx, b = 2t*sy, c = t*(sx^2+sy^2)
// so that t*||p - s||^2 = (c + q_m) - a*px - b*py with q_m = t*||p||^2.
// One dwordx4 load per sample in the hot kernel.
__global__ __launch_bounds__(256, 8) void prescale_kernel(
    const float* __restrict__ inputs,   // (B*N, 2)
    float4* __restrict__ D,
    int total, float t2, float t)
{
    int i = blockIdx.x * 256 + (int)threadIdx.x;
    if (i < total) {
        float2 s = reinterpret_cast<const float2*>(inputs)[i];
        D[i] = make_float4(t2 * s.x, t2 * s.y, t * fmaf(s.x, s.x, s.y * s.y), 0.f);
    }
}

// out[b,m] = coefN * sum_n exp2(a_n*px + b_n*py - (c_n + q_m))
__global__ __launch_bounds__(BLOCK, 4) void kde_kernel(
    const float4* __restrict__ D,       // (B*N) packed a,b,c
    const float* __restrict__ points,   // (M, 2)
    float* __restrict__ out,            // (B, M), pre-zeroed
    int N, int M, int nPerBlock, float t, float coefN)
{
    const int b    = blockIdx.y;
    const int base = b * N + blockIdx.x * nPerBlock;
    const int tid  = (int)threadIdx.x;

    const float2* pts = reinterpret_cast<const float2*>(points);
    float px[MPT], py[MPT], q[MPT];
#pragma unroll
    for (int k = 0; k < MPT; ++k) {
        int m = tid + k * BLOCK;
        float2 p = pts[m < M ? m : 0];
        px[k] = p.x;
        py[k] = p.y;
        q[k]  = t * fmaf(p.x, p.x, p.y * p.y);
    }

    float acc[MPT];
#pragma unroll
    for (int k = 0; k < MPT; ++k) acc[k] = 0.f;

    for (int i0 = 0; i0 < nPerBlock; i0 += CHUNK) {
        float4 s[CHUNK];
#pragma unroll
        for (int j = 0; j < CHUNK; ++j) s[j] = D[base + i0 + j];  // uniform addr
#pragma unroll
        for (int j = 0; j < CHUNK; ++j) {
            const float a = s[j].x, bb = s[j].y, c = s[j].z;
#pragma unroll
            for (int k = 0; k < MPT; ++k) {
                float w = fmaf(a, px[k], fmaf(bb, py[k], -(c + q[k])));
                acc[k] += EXP2F(w);
            }
        }
    }

#pragma unroll
    for (int k = 0; k < MPT; ++k) {
        int m = tid + k * BLOCK;
        if (m < M) atomicAdd(&out[(size_t)b * M + m], acc[k] * coefN);
    }
}

extern "C" void kernel_launch(void* const* d_in, const int* in_sizes, int n_in,
                              void* d_out, int out_size, void* d_ws, size_t ws_size,
                              hipStream_t stream) {
    const float* inputs = (const float*)d_in[0];   // (B, N, 2) fp32
    const float* points = (const float*)d_in[1];   // (M, 2) fp32
    float* out = (float*)d_out;                    // (B, M) fp32

    const int M = in_sizes[1] / 2;          // 512
    const int B = out_size / M;             // 128
    const int N = in_sizes[0] / (2 * B);    // 2048
    const int total = B * N;                // 262144

    // Silverman bandwidth, d = 2
    const double h    = pow(4.0 / 4.0, 1.0 / 6.0) * pow((double)N, -1.0 / 6.0);
    const double h2   = h * h;
    const double coef = 1.0 / (2.0 * M_PI * h2);
    const double td   = 0.5 / (h2 * M_LN2);       // exp(-0.5*sq/h^2) = exp2(-t*sq)
    const float  t     = (float)td;
    const float  t2    = (float)(2.0 * td);
    const float  coefN = (float)(coef / (double)N);

    float4* D = (float4*)d_ws;

    hipMemsetAsync(out, 0, (size_t)out_size * sizeof(float), stream);

    prescale_kernel<<<(total + 255) / 256, 256, 0, stream>>>(inputs, D, total, t2, t);

    const int nPerBlock = N / NSPLIT;       // 128
    dim3 grid(NSPLIT, B);
    kde_kernel<<<grid, BLOCK, 0, stream>>>(D, points, out, N, M, nPerBlock, t, coefN);
}

// Round 4
// 80.435 us; speedup vs baseline: 1.0470x; 1.0470x over previous
//
#include <hip/hip_runtime.h>
#include <math.h>

#define BLOCK 128
#define MPT 4          // m-points per thread (BLOCK * MPT = M = 512)
#define NSPLIT 32
#define CHUNK 4

#if __has_builtin(__builtin_amdgcn_exp2f)
#define EXP2F(x) __builtin_amdgcn_exp2f(x)
#else
#define EXP2F(x) exp2f(x)
#endif

typedef float v2f __attribute__((ext_vector_type(2)));
static __device__ __forceinline__ v2f splat2(float v) { v2f r; r.x = v; r.y = v; return r; }

// Precompute per-sample constants packed as float4:
//   a = 2t*sx, b = 2t*sy, c = t*(sx^2+sy^2)
// so that t*||p - s||^2 = (c + q_m) - a*px - b*py with q_m = t*||p||^2.
__global__ __launch_bounds__(256, 8) void prescale_kernel(
    const float* __restrict__ inputs,   // (B*N, 2)
    float4* __restrict__ D,
    int total, float t2, float t)
{
    int i = blockIdx.x * 256 + (int)threadIdx.x;
    if (i < total) {
        float2 s = reinterpret_cast<const float2*>(inputs)[i];
        D[i] = make_float4(t2 * s.x, t2 * s.y, t * fmaf(s.x, s.x, s.y * s.y), 0.f);
    }
}

// out[b,m] = coefN * sum_n exp2(a_n*px + b_n*py - (c_n + q_m))
// Packed-fp32 math across m-pairs; register double-buffered sample chunks.
__global__ __launch_bounds__(BLOCK, 8) void kde_kernel(
    const float4* __restrict__ D,       // (B*N) packed a,b,c
    const float* __restrict__ points,   // (M, 2)
    float* __restrict__ out,            // (B, M), pre-zeroed
    int N, int M, int nPerBlock, float t, float coefN)
{
    const int b    = blockIdx.y;
    const int base = b * N + blockIdx.x * nPerBlock;
    const int tid  = (int)threadIdx.x;

    const float2* pts = reinterpret_cast<const float2*>(points);
    float px[MPT], py[MPT], q[MPT];
#pragma unroll
    for (int k = 0; k < MPT; ++k) {
        int m = tid + k * BLOCK;
        float2 p = pts[m < M ? m : 0];
        px[k] = p.x;
        py[k] = p.y;
        q[k]  = t * fmaf(p.x, p.x, p.y * p.y);
    }
    v2f PX0, PY0, Q0, PX1, PY1, Q1;
    PX0.x = px[0]; PX0.y = px[1]; PY0.x = py[0]; PY0.y = py[1];
    Q0.x = q[0];   Q0.y = q[1];
    PX1.x = px[2]; PX1.y = px[3]; PY1.x = py[2]; PY1.y = py[3];
    Q1.x = q[2];   Q1.y = q[3];

    v2f acc0 = splat2(0.f), acc1 = splat2(0.f);

    float4 cur[CHUNK], nxt[CHUNK];
#pragma unroll
    for (int j = 0; j < CHUNK; ++j) cur[j] = D[base + j];

    for (int i0 = 0; i0 < nPerBlock; i0 += CHUNK) {
        const int inext = i0 + CHUNK;
        const bool more = inext < nPerBlock;
        // Prefetch next chunk (re-reads chunk 0 harmlessly on the last iter;
        // keeps the address in-bounds without a branch around the loads).
#pragma unroll
        for (int j = 0; j < CHUNK; ++j) nxt[j] = D[base + (more ? inext + j : j)];

#pragma unroll
        for (int j = 0; j < CHUNK; ++j) {
            const v2f A = splat2(cur[j].x);
            const v2f Bv = splat2(cur[j].y);
            const v2f C = splat2(cur[j].z);
            v2f w0 = __builtin_elementwise_fma(A, PX0,
                         __builtin_elementwise_fma(Bv, PY0, -(C + Q0)));
            v2f w1 = __builtin_elementwise_fma(A, PX1,
                         __builtin_elementwise_fma(Bv, PY1, -(C + Q1)));
            v2f e0, e1;
            e0.x = EXP2F(w0.x); e0.y = EXP2F(w0.y);
            e1.x = EXP2F(w1.x); e1.y = EXP2F(w1.y);
            acc0 += e0;
            acc1 += e1;
        }
#pragma unroll
        for (int j = 0; j < CHUNK; ++j) cur[j] = nxt[j];
    }

    float res[MPT];
    res[0] = acc0.x; res[1] = acc0.y; res[2] = acc1.x; res[3] = acc1.y;
#pragma unroll
    for (int k = 0; k < MPT; ++k) {
        int m = tid + k * BLOCK;
        if (m < M) atomicAdd(&out[(size_t)b * M + m], res[k] * coefN);
    }
}

extern "C" void kernel_launch(void* const* d_in, const int* in_sizes, int n_in,
                              void* d_out, int out_size, void* d_ws, size_t ws_size,
                              hipStream_t stream) {
    const float* inputs = (const float*)d_in[0];   // (B, N, 2) fp32
    const float* points = (const float*)d_in[1];   // (M, 2) fp32
    float* out = (float*)d_out;                    // (B, M) fp32

    const int M = in_sizes[1] / 2;          // 512
    const int B = out_size / M;             // 128
    const int N = in_sizes[0] / (2 * B);    // 2048
    const int total = B * N;                // 262144

    // Silverman bandwidth, d = 2
    const double h    = pow(4.0 / 4.0, 1.0 / 6.0) * pow((double)N, -1.0 / 6.0);
    const double h2   = h * h;
    const double coef = 1.0 / (2.0 * M_PI * h2);
    const double td   = 0.5 / (h2 * M_LN2);       // exp(-0.5*sq/h^2) = exp2(-t*sq)
    const float  t     = (float)td;
    const float  t2    = (float)(2.0 * td);
    const float  coefN = (float)(coef / (double)N);

    float4* D = (float4*)d_ws;

    hipMemsetAsync(out, 0, (size_t)out_size * sizeof(float), stream);

    prescale_kernel<<<(total + 255) / 256, 256, 0, stream>>>(inputs, D, total, t2, t);

    const int nPerBlock = N / NSPLIT;       // 64
    dim3 grid(NSPLIT, B);
    kde_kernel<<<grid, BLOCK, 0, stream>>>(D, points, out, N, M, nPerBlock, t, coefN);
}

// Round 5
// 78.360 us; speedup vs baseline: 1.0748x; 1.0265x over previous
//
#include <hip/hip_runtime.h>
#include <math.h>

#define BLOCK 256
#define MPT 2          // m-points per thread (BLOCK * MPT = M = 512)
#define NSPLIT 16
#define CHUNK 16

#if __has_builtin(__builtin_amdgcn_exp2f)
#define EXP2F(x) __builtin_amdgcn_exp2f(x)
#else
#define EXP2F(x) exp2f(x)
#endif

typedef float v2f __attribute__((ext_vector_type(2)));

// Precompute per-sample constants packed as float4:
//   a = 2t*sx, b = 2t*sy, c = t*(sx^2+sy^2)
// so that t*||p - s||^2 = (c + q_m) - a*px - b*py with q_m = t*||p||^2.
__global__ __launch_bounds__(256, 8) void prescale_kernel(
    const float* __restrict__ inputs,   // (B*N, 2)
    float4* __restrict__ D,
    int total, float t2, float t)
{
    int i = blockIdx.x * 256 + (int)threadIdx.x;
    if (i < total) {
        float2 s = reinterpret_cast<const float2*>(inputs)[i];
        D[i] = make_float4(t2 * s.x, t2 * s.y, t * fmaf(s.x, s.x, s.y * s.y), 0.f);
    }
}

// out[b,m] = coefN * sum_n exp2(a_n*px + b_n*py - (c_n + q_m))
// Sample constants stay in SGPRs (uniform s_load) and broadcast into
// v_pk_* ops; per-thread VGPR state is ~25 regs -> full 32 waves/CU.
__global__ __launch_bounds__(BLOCK, 8) void kde_kernel(
    const float4* __restrict__ D,       // (B*N) packed a,b,c
    const float* __restrict__ points,   // (M, 2)
    float* __restrict__ out,            // (B, M), pre-zeroed
    int N, int M, int nPerBlock, float t, float coefN)
{
    const int b    = blockIdx.y;
    const int base = b * N + blockIdx.x * nPerBlock;
    const int tid  = (int)threadIdx.x;
    const int m0   = tid;
    const int m1   = tid + BLOCK;

    const float2* pts = reinterpret_cast<const float2*>(points);
    float2 p0 = pts[m0 < M ? m0 : 0];
    float2 p1 = pts[m1 < M ? m1 : 0];

    v2f PX, PY, Q;
    PX.x = p0.x; PX.y = p1.x;
    PY.x = p0.y; PY.y = p1.y;
    Q.x  = t * fmaf(p0.x, p0.x, p0.y * p0.y);
    Q.y  = t * fmaf(p1.x, p1.x, p1.y * p1.y);

    v2f acc; acc.x = 0.f; acc.y = 0.f;

    for (int i0 = 0; i0 < nPerBlock; i0 += CHUNK) {
#pragma unroll
        for (int j = 0; j < CHUNK; ++j) {
            const float4 s = D[base + i0 + j];   // uniform -> s_load, SGPRs
            v2f A;  A.x = s.x;  A.y = s.x;       // SGPR broadcast, no movs
            v2f Bv; Bv.x = s.y; Bv.y = s.y;
            v2f C;  C.x = s.z;  C.y = s.z;
            v2f w = __builtin_elementwise_fma(A, PX,
                        __builtin_elementwise_fma(Bv, PY, -(C + Q)));
            v2f e;
            e.x = EXP2F(w.x);
            e.y = EXP2F(w.y);
            acc += e;
        }
    }

    if (m0 < M) atomicAdd(&out[(size_t)b * M + m0], acc.x * coefN);
    if (m1 < M) atomicAdd(&out[(size_t)b * M + m1], acc.y * coefN);
}

extern "C" void kernel_launch(void* const* d_in, const int* in_sizes, int n_in,
                              void* d_out, int out_size, void* d_ws, size_t ws_size,
                              hipStream_t stream) {
    const float* inputs = (const float*)d_in[0];   // (B, N, 2) fp32
    const float* points = (const float*)d_in[1];   // (M, 2) fp32
    float* out = (float*)d_out;                    // (B, M) fp32

    const int M = in_sizes[1] / 2;          // 512
    const int B = out_size / M;             // 128
    const int N = in_sizes[0] / (2 * B);    // 2048
    const int total = B * N;                // 262144

    // Silverman bandwidth, d = 2
    const double h    = pow(4.0 / 4.0, 1.0 / 6.0) * pow((double)N, -1.0 / 6.0);
    const double h2   = h * h;
    const double coef = 1.0 / (2.0 * M_PI * h2);
    const double td   = 0.5 / (h2 * M_LN2);       // exp(-0.5*sq/h^2) = exp2(-t*sq)
    const float  t     = (float)td;
    const float  t2    = (float)(2.0 * td);
    const float  coefN = (float)(coef / (double)N);

    float4* D = (float4*)d_ws;

    hipMemsetAsync(out, 0, (size_t)out_size * sizeof(float), stream);

    prescale_kernel<<<(total + 255) / 256, 256, 0, stream>>>(inputs, D, total, t2, t);

    const int nPerBlock = N / NSPLIT;       // 128
    dim3 grid(NSPLIT, B);
    kde_kernel<<<grid, BLOCK, 0, stream>>>(D, points, out, N, M, nPerBlock, t, coefN);
}